// Round 2
// baseline (139.504 us; speedup 1.0000x reference)
//
#include <hip/hip_runtime.h>
#include <stdint.h>

#define SEQ  2048
#define DIMC 256
#define HID  512
#define NH   8
#define DH   64

typedef __attribute__((ext_vector_type(8))) short bf16x8;
typedef __attribute__((ext_vector_type(4))) float f32x4;
typedef __attribute__((ext_vector_type(16))) float f32x16;
typedef __attribute__((ext_vector_type(2))) unsigned uint2v;
typedef __attribute__((address_space(1))) const uint32_t guint_t;
typedef __attribute__((address_space(3))) uint32_t luint_t;

// async global->LDS, 16B per lane; LDS dest = wave-uniform base + lane*16
__device__ __forceinline__ void gld16(const void* g, void* l) {
  __builtin_amdgcn_global_load_lds((guint_t*)g, (luint_t*)l, 16, 0, 0);
}

// raw barrier: no compiler-inserted vmcnt(0) drain (unlike __syncthreads)
__device__ __forceinline__ void barrier_raw() {
  asm volatile("" ::: "memory");
  __builtin_amdgcn_s_barrier();
  asm volatile("" ::: "memory");
}
#define WAITVM(n) asm volatile("s_waitcnt vmcnt(" #n ")" ::: "memory")

__device__ __forceinline__ unsigned short f2bf(float f) {
  union { float f; uint32_t u; } v; v.f = f;
  return (unsigned short)((v.u + 0x7FFFu + ((v.u >> 16) & 1u)) >> 16);
}

__device__ __forceinline__ uint32_t fbits(float f) {
  union { float f; uint32_t u; } v; v.f = f; return v.u;
}

// pack two fp32 (raw bits) -> (bf16,bf16) dword, round-half-up
__device__ __forceinline__ uint32_t pku(uint32_t u0, uint32_t u1) {
  return __builtin_amdgcn_perm(u1 + 0x8000u, u0 + 0x8000u, 0x07060302u);
}

// exchange hi 32 lanes of a with lo 32 lanes of b:
// a' = {a.lo, b.lo}, b' = {a.hi, b.hi}
__device__ __forceinline__ void swap32(uint32_t& a, uint32_t& b) {
#if __has_builtin(__builtin_amdgcn_permlane32_swap)
  uint2v r = __builtin_amdgcn_permlane32_swap(a, b, false, false);
  a = r[0]; b = r[1];
#else
  uint32_t aw = __shfl_xor(a, 32);
  uint32_t bw = __shfl_xor(b, 32);
  bool lo = (threadIdx.x & 32) == 0;
  uint32_t an = lo ? a : bw;
  uint32_t bn = lo ? aw : b;
  a = an; b = bn;
#endif
}

// ---------------------------------------------------------------------------
// prep: w_qkv -> bf16 (Q rows pre-scaled by SCALE*log2e), w_out -> bf16,
//       x [b][i][n] fp32 -> xT [b][n][i] bf16
// ---------------------------------------------------------------------------
__global__ __launch_bounds__(256) void prep_kernel(
    const float* __restrict__ x, const float* __restrict__ wqkv,
    const float* __restrict__ wout,
    unsigned short* __restrict__ wqkv_b, unsigned short* __restrict__ wout_b,
    unsigned short* __restrict__ xT) {
  __shared__ float tile[64][65];
  int blk = blockIdx.x;
  int t = threadIdx.x;
  if (blk < 384) {
    int idx = blk * 1024 + t * 4;
    float4 v = *(const float4*)(wqkv + idx);
    float s = ((idx >> 8) < HID) ? 0.18033688011112042f : 1.0f;  // 0.125*log2(e)
    ushort4 o;
    o.x = f2bf(v.x * s); o.y = f2bf(v.y * s);
    o.z = f2bf(v.z * s); o.w = f2bf(v.w * s);
    *(ushort4*)(wqkv_b + idx) = o;
    return;
  }
  if (blk < 512) {
    int idx = (blk - 384) * 1024 + t * 4;
    float4 v = *(const float4*)(wout + idx);
    ushort4 o;
    o.x = f2bf(v.x); o.y = f2bf(v.y); o.z = f2bf(v.z); o.w = f2bf(v.w);
    *(ushort4*)(wout_b + idx) = o;
    return;
  }
  int tid = blk - 512;
  int b  = tid >> 7;
  int r  = tid & 127;
  int i0 = (r >> 5) * 64;
  int n0 = (r & 31) * 64;
  const float* xb = x + (size_t)b * DIMC * SEQ;
  int tn = t & 15, ti = t >> 4;
#pragma unroll
  for (int j = 0; j < 4; j++) {
    int il = ti + j * 16;
    float4 v = *(const float4*)(xb + (size_t)(i0 + il) * SEQ + n0 + tn * 4);
    tile[il][tn*4+0] = v.x; tile[il][tn*4+1] = v.y;
    tile[il][tn*4+2] = v.z; tile[il][tn*4+3] = v.w;
  }
  __syncthreads();
  unsigned short* xTb = xT + (size_t)b * SEQ * DIMC;
#pragma unroll
  for (int j = 0; j < 4; j++) {
    int nl = ti + j * 16;
    int i4 = tn * 4;
    uint2 pk;
    pk.x = (uint32_t)f2bf(tile[i4+0][nl]) | ((uint32_t)f2bf(tile[i4+1][nl]) << 16);
    pk.y = (uint32_t)f2bf(tile[i4+2][nl]) | ((uint32_t)f2bf(tile[i4+3][nl]) << 16);
    *(uint2*)(xTb + (size_t)(n0 + nl) * DIMC + i0 + i4) = pk;
  }
}

// ---------------------------------------------------------------------------
// qkv_gemm: [1536,256]x[256,2048] per batch, 128x128 tile, BK=64.
// Double-buffered global_load_lds staging, raw barriers + counted vmcnt.
// ---------------------------------------------------------------------------
__global__ __launch_bounds__(256, 2) void qkv_gemm(
    const unsigned short* __restrict__ wq, const unsigned short* __restrict__ xT,
    unsigned short* __restrict__ Qs, unsigned short* __restrict__ Ks,
    unsigned short* __restrict__ Vt) {
  __shared__ unsigned short lds[32768];
  int o0 = blockIdx.x * 128;
  int n0 = blockIdx.y * 128;
  int b  = blockIdx.z;
  int t  = threadIdx.x;
  int wv = t >> 6, l = t & 63, l15 = l & 15, q = l >> 4;
  int wm = (wv & 1) * 64, wn = (wv >> 1) * 64;
  f32x4 acc[4][4];
#pragma unroll
  for (int i = 0; i < 4; i++)
#pragma unroll
    for (int j = 0; j < 4; j++) acc[i][j] = (f32x4){0.f, 0.f, 0.f, 0.f};
  const unsigned short* Ag = wq + (size_t)o0 * DIMC;
  const unsigned short* Bg = xT + ((size_t)b * SEQ + n0) * DIMC;
  int lrow8 = l >> 3, lcol = l & 7;

  auto stage = [&](int kk, int buf) {
    unsigned short* la = lds + (buf << 14);
    unsigned short* lb = la + 8192;
    int k0 = kk * 64;
#pragma unroll
    for (int c0 = 0; c0 < 4; c0++) {
      int c = wv * 4 + c0;
      int row = c * 8 + lrow8;
      int sg = lcol ^ (row & 7);
      gld16(Ag + (size_t)row * DIMC + k0 + sg * 8, la + c * 512);
      gld16(Bg + (size_t)row * DIMC + k0 + sg * 8, lb + c * 512);
    }
  };

  stage(0, 0);
  for (int kk = 0; kk < 4; kk++) {
    int cur = kk & 1;
    if (kk < 3) { stage(kk + 1, cur ^ 1); WAITVM(8); }
    else        { WAITVM(0); }
    barrier_raw();
    unsigned short* la = lds + (cur << 14);
    unsigned short* lb = la + 8192;
#pragma unroll
    for (int kh = 0; kh < 2; kh++) {
      bf16x8 af[4], bfr[4];
#pragma unroll
      for (int mt = 0; mt < 4; mt++) {
        int row = wm + mt*16 + l15;
        af[mt] = *(const bf16x8*)(la + row*64 + ((kh*4 + q) ^ (row & 7)) * 8);
      }
#pragma unroll
      for (int nt = 0; nt < 4; nt++) {
        int row = wn + nt*16 + l15;
        bfr[nt] = *(const bf16x8*)(lb + row*64 + ((kh*4 + q) ^ (row & 7)) * 8);
      }
#pragma unroll
      for (int mt = 0; mt < 4; mt++)
#pragma unroll
        for (int nt = 0; nt < 4; nt++)
          acc[mt][nt] = __builtin_amdgcn_mfma_f32_16x16x32_bf16(af[mt], bfr[nt], acc[mt][nt], 0, 0, 0);
    }
    barrier_raw();
  }
  int seg3 = o0 >> 9;            // 0=Q, 1=K, 2=V
  int h0   = (o0 & 511) >> 6;
  if (seg3 == 2) {
#pragma unroll
    for (int mt = 0; mt < 4; mt++)
#pragma unroll
      for (int nt = 0; nt < 4; nt++)
#pragma unroll
        for (int r = 0; r < 4; r++) {
          int ol = wm + mt * 16 + q * 4 + r;
          int h = h0 + (ol >> 6), d = ol & 63;
          int n = n0 + wn + nt * 16 + l15;
          Vt[(((size_t)b * NH + h) * DH + d) * SEQ + n] = f2bf(acc[mt][nt][r]);
        }
  } else {
    unsigned short* dst = (seg3 == 0) ? Qs : Ks;
#pragma unroll
    for (int mt = 0; mt < 4; mt++)
#pragma unroll
      for (int nt = 0; nt < 4; nt++)
#pragma unroll
        for (int r = 0; r < 4; r++) {
          int ol = wm + mt * 16 + q * 4 + r;
          int nn = wn + nt * 16 + l15;
          lds[nn * 136 + ol] = f2bf(acc[mt][nt][r]);
        }
    __syncthreads();
#pragma unroll
    for (int i = 0; i < 8; i++) {
      int idx = i * 256 + t;
      int nn  = idx >> 4;
      int olb = (idx & 15) * 8;
      uint4 v = *(const uint4*)(lds + nn * 136 + olb);
      int h = h0 + (olb >> 6), d = olb & 63;
      *(uint4*)(dst + (((size_t)b * NH + h) * SEQ + n0 + nn) * DH + d) = v;
    }
  }
}

// ---------------------------------------------------------------------------
// attn: 32x32x16 MFMA. Finer split for TLP: q-tile 64, kv-split-2 per block.
// Grid 1024 blocks (XCD-swizzled: 4 bh pinned per XCD so K/V stay L2-resident)
// x 4 waves: wave (cg=w&1, qg=w>>1) computes 32 q x 1024 keys, 32 keys/iter.
// 4 blocks/CU = 16 waves/CU (vs 8 before) to fill the VALU/MFMA pipes that
// the serial QK->exp2->pack->PV chain leaves idle at 2 waves/SIMD.
// Double-buffered gld16 staging, counted vmcnt, additive 2-chunk combine.
// ---------------------------------------------------------------------------
__global__ __launch_bounds__(256, 4) void attn_kernel(
    const unsigned short* __restrict__ Qs, const unsigned short* __restrict__ Ks,
    const unsigned short* __restrict__ Vt, unsigned short* __restrict__ AO) {
  __shared__ unsigned short KVs[16384];  // 2 buf x (K[2][32][64] | V[2][64][32]) = 32KB
  __shared__ float Lc[128];              // row-sum partials [cg][64 q]
  // XCD swizzle: id&7 = XCD slot; 4 bh x 32 q-tiles per XCD -> K/V L2-resident
  int id = blockIdx.x;
  int s  = id >> 3;
  int bh = (id & 7) * 4 + (s & 3);
  int q0 = (s >> 2) * 64;
  int b = bh >> 3, h = bh & 7;
  int t = threadIdx.x;
  int w = t >> 6, l = t & 63, l31 = l & 31, lh = l >> 5;
  int cg = w & 1, qg = w >> 1;
  // Q B-frags (n=query=l31, k=head-dim) straight from global, once
  const unsigned short* Qg = Qs + ((size_t)bh * SEQ + q0 + qg * 32) * DH;
  bf16x8 qb[4];
#pragma unroll
  for (int kc = 0; kc < 4; kc++)
    qb[kc] = *(const bf16x8*)(Qg + l31 * DH + kc*16 + lh*8);
  f32x16 oacc[2];
  float lsum = 0.f;
#pragma unroll
  for (int dt = 0; dt < 2; dt++)
#pragma unroll
    for (int r = 0; r < 16; r++) oacc[dt][r] = 0.f;

  const unsigned short* Ksrc = Ks + ((size_t)bh * SEQ + cg * 1024) * DH;
  const unsigned short* Vsrc = Vt + (size_t)bh * DH * SEQ + cg * 1024;

  auto stage = [&](int it2, int buf) {
    int jb = it2 * 32;
    unsigned short* base = KVs + buf * 8192;
    if (w < 2) {                           // stage K chunk cg: 32 keys x 128B
      const unsigned short* src = Ksrc + (size_t)jb * DH;
      unsigned short* dst = base + cg * 2048;
#pragma unroll
      for (int g = 0; g < 4; g++) {
        int kr = g * 8 + (l >> 3);
        gld16(src + (size_t)kr * DH + ((l & 7) ^ (kr & 7)) * 8, dst + g * 512);
      }
    } else {                               // stage V chunk cg: 64 d-rows x 64B
      const unsigned short* src = Vsrc + jb;
      unsigned short* dst = base + 4096 + cg * 2048;
#pragma unroll
      for (int g = 0; g < 4; g++) {
        int dr = g * 16 + (l >> 2);
        gld16(src + (size_t)dr * SEQ + ((l & 3) ^ (dr & 3)) * 8, dst + g * 512);
      }
    }
  };

  stage(0, 0);
  for (int it = 0; it < 32; it++) {
    int cur = it & 1;
    if (it < 31) { stage(it + 1, cur ^ 1); WAITVM(4); }  // next tile stays in flight
    else         { WAITVM(0); }
    barrier_raw();                         // cur tile fully in LDS (all waves)
    const unsigned short* Kst = KVs + cur * 8192 + cg * 2048;
    const unsigned short* Vst = KVs + cur * 8192 + 4096 + cg * 2048;
    // S^T = K Q^T : A = K (m=key 32), B = Q (n=query 32)
    f32x16 st;
#pragma unroll
    for (int r = 0; r < 16; r++) st[r] = 0.f;
#pragma unroll
    for (int kc = 0; kc < 4; kc++) {
      bf16x8 kf = *(const bf16x8*)(Kst + l31 * 64 + (((kc*2 + lh)) ^ (l31 & 7)) * 8);
      st = __builtin_amdgcn_mfma_f32_32x32x16_bf16(kf, qb[kc], st, 0, 0, 0);
    }
    // V B-frags (n=d, k=key 32)
    bf16x8 vf[2][2];
#pragma unroll
    for (int kc2 = 0; kc2 < 2; kc2++)
#pragma unroll
      for (int dt = 0; dt < 2; dt++)
        vf[kc2][dt] = *(const bf16x8*)(Vst + (dt*32 + l31) * 32 +
                                       (((kc2*2 + lh)) ^ (l31 & 3)) * 8);
    // p = exp2(s); row-sum partial (col=query=l31 per lane)
    float p[16];
    float s0 = 0.f;
#pragma unroll
    for (int r = 0; r < 16; r++) { p[r] = __builtin_amdgcn_exp2f(st[r]); s0 += p[r]; }
    lsum += s0;
    // D-layout -> A-layout in registers (permlane32_swap + bf16 pack)
    bf16x8 af[2];
#pragma unroll
    for (int hf = 0; hf < 2; hf++) {
      uint32_t xs[4], ys[4];
#pragma unroll
      for (int j = 0; j < 4; j++) {
        xs[j] = fbits(p[hf*8 + j]);
        ys[j] = fbits(p[hf*8 + 4 + j]);
        swap32(xs[j], ys[j]);
      }
      uint32_t d0 = pku(xs[0], xs[1]);
      uint32_t d1 = pku(xs[2], xs[3]);
      uint32_t d2 = pku(ys[0], ys[1]);
      uint32_t d3 = pku(ys[2], ys[3]);
      union { uint32_t u[4]; bf16x8 v; } cv;
      cv.u[0] = d0; cv.u[1] = d1; cv.u[2] = d2; cv.u[3] = d3;
      af[hf] = cv.v;
    }
#pragma unroll
    for (int kc2 = 0; kc2 < 2; kc2++)
#pragma unroll
      for (int dt = 0; dt < 2; dt++)
        oacc[dt] = __builtin_amdgcn_mfma_f32_32x32x16_bf16(af[kc2], vf[kc2][dt], oacc[dt], 0, 0, 0);
    barrier_raw();                         // all reads of cur done -> overwritable
  }
  // ---- combine the two kv-chunks (purely additive; no max-rescale) ----
  {
    float v = lsum;
    v += __shfl_xor(v, 32);                // lo/hi halves hold disjoint keys
    if (l < 32) Lc[cg * 64 + qg * 32 + l31] = v;
  }
  __syncthreads();
  float* Oc = (float*)KVs;                 // [64 q][64 d] fp32 = 16 KB
  if (cg == 1) {
#pragma unroll
    for (int dt = 0; dt < 2; dt++)
#pragma unroll
      for (int r = 0; r < 16; r++) {
        int qrow = qg*32 + (r & 3) + 8*(r >> 2) + 4*lh;
        Oc[qrow * 64 + dt*32 + l31] = oacc[dt][r];
      }
  }
  __syncthreads();
  if (cg == 0) {
    unsigned short* AOb = AO + (size_t)b * SEQ * HID + h * DH;
#pragma unroll
    for (int r = 0; r < 16; r++) {
      int qrow = qg*32 + (r & 3) + 8*(r >> 2) + 4*lh;
      float inv = __builtin_amdgcn_rcpf(Lc[qrow] + Lc[64 + qrow]);
      int n = q0 + qrow;
#pragma unroll
      for (int dt = 0; dt < 2; dt++) {
        float val = (oacc[dt][r] + Oc[qrow * 64 + dt*32 + l31]) * inv;
        AOb[(size_t)n * HID + dt*32 + l31] = f2bf(val);
      }
    }
  }
}

// ---------------------------------------------------------------------------
// out_gemm: [256,512] x AO^T -> out[b][256][2048] fp32 + bias
// Double-buffered global_load_lds staging.
// ---------------------------------------------------------------------------
__global__ __launch_bounds__(256, 2) void out_gemm(
    const unsigned short* __restrict__ wo, const unsigned short* __restrict__ AO,
    const float* __restrict__ bias, float* __restrict__ out) {
  __shared__ unsigned short lds[24576];
  int o0 = blockIdx.x * 64;
  int n0 = blockIdx.y * 128;
  int b  = blockIdx.z;
  int t  = threadIdx.x;
  int wv = t >> 6, l = t & 63, l15 = l & 15, q = l >> 4;
  int wm = (wv & 1) * 32, wn = (wv >> 1) * 64;
  f32x4 acc[2][4];
#pragma unroll
  for (int i = 0; i < 2; i++)
#pragma unroll
    for (int j = 0; j < 4; j++) acc[i][j] = (f32x4){0.f,0.f,0.f,0.f};
  const unsigned short* Ag = wo + (size_t)o0 * HID;
  const unsigned short* Bg = AO + ((size_t)b * SEQ + n0) * HID;
  int lrow8 = l >> 3, lcol = l & 7;

  auto stage = [&](int kk, int buf) {
    unsigned short* la = lds + buf * 12288;
    unsigned short* lb = la + 4096;
    int k0 = kk * 64;
#pragma unroll
    for (int c0 = 0; c0 < 2; c0++) {       // A: 8 chunks
      int c = wv * 2 + c0;
      int row = c * 8 + lrow8;
      int sg = lcol ^ (row & 7);
      gld16(Ag + (size_t)row * HID + k0 + sg * 8, la + c * 512);
    }
#pragma unroll
    for (int c0 = 0; c0 < 4; c0++) {       // B: 16 chunks
      int c = wv * 4 + c0;
      int row = c * 8 + lrow8;
      int sg = lcol ^ (row & 7);
      gld16(Bg + (size_t)row * HID + k0 + sg * 8, lb + c * 512);
    }
  };

  stage(0, 0);
  for (int kk = 0; kk < 8; kk++) {
    int cur = kk & 1;
    if (kk < 7) { stage(kk + 1, cur ^ 1); WAITVM(6); }
    else        { WAITVM(0); }
    barrier_raw();
    unsigned short* la = lds + cur * 12288;
    unsigned short* lb = la + 4096;
#pragma unroll
    for (int kh = 0; kh < 2; kh++) {
      bf16x8 af[2], bfr[4];
#pragma unroll
      for (int mt = 0; mt < 2; mt++) {
        int row = wm + mt*16 + l15;
        af[mt] = *(const bf16x8*)(la + row*64 + ((kh*4 + q) ^ (row & 7)) * 8);
      }
#pragma unroll
      for (int nt = 0; nt < 4; nt++) {
        int row = wn + nt*16 + l15;
        bfr[nt] = *(const bf16x8*)(lb + row*64 + ((kh*4 + q) ^ (row & 7)) * 8);
      }
#pragma unroll
      for (int mt = 0; mt < 2; mt++)
#pragma unroll
        for (int nt = 0; nt < 4; nt++)
          acc[mt][nt] = __builtin_amdgcn_mfma_f32_16x16x32_bf16(af[mt], bfr[nt], acc[mt][nt], 0,0,0);
    }
    barrier_raw();
  }
#pragma unroll
  for (int mt = 0; mt < 2; mt++)
#pragma unroll
    for (int nt = 0; nt < 4; nt++)
#pragma unroll
      for (int r = 0; r < 4; r++) {
        int o2 = o0 + wm + mt*16 + q*4 + r;
        int n  = n0 + wn + nt*16 + l15;
        out[((size_t)b * DIMC + o2) * SEQ + n] = acc[mt][nt][r] + bias[o2];
      }
}

extern "C" void kernel_launch(void* const* d_in, const int* in_sizes, int n_in,
                              void* d_out, int out_size, void* d_ws, size_t ws_size,
                              hipStream_t stream) {
  const float* x    = (const float*)d_in[0];
  const float* wqkv = (const float*)d_in[1];
  const float* wout = (const float*)d_in[2];
  const float* bout = (const float*)d_in[3];
  float* out = (float*)d_out;
  char* ws = (char*)d_ws;
  unsigned short* wqkv_b = (unsigned short*)(ws);
  unsigned short* wout_b = (unsigned short*)(ws + 786432);
  unsigned short* xT     = (unsigned short*)(ws + 1048576);
  unsigned short* Qs     = (unsigned short*)(ws + 5242880);
  unsigned short* Ks     = (unsigned short*)(ws + 13631488);
  unsigned short* Vt     = (unsigned short*)(ws + 22020096);
  unsigned short* AO     = (unsigned short*)(ws + 30408704);
  prep_kernel<<<1024, 256, 0, stream>>>(x, wqkv, wout, wqkv_b, wout_b, xT);
  qkv_gemm<<<dim3(12, 16, 4), 256, 0, stream>>>(wqkv_b, xT, Qs, Ks, Vt);
  attn_kernel<<<1024, 256, 0, stream>>>(Qs, Ks, Vt, AO);
  out_gemm<<<dim3(4, 16, 4), 256, 0, stream>>>(wout_b, AO, bout, out);
}

// Round 4
// 139.074 us; speedup vs baseline: 1.0031x; 1.0031x over previous
//
#include <hip/hip_runtime.h>
#include <stdint.h>

#define SEQ  2048
#define DIMC 256
#define HID  512
#define NH   8
#define DH   64

typedef __attribute__((ext_vector_type(8))) short bf16x8;
typedef __attribute__((ext_vector_type(4))) float f32x4;
typedef __attribute__((ext_vector_type(16))) float f32x16;
typedef __attribute__((ext_vector_type(2))) unsigned uint2v;
typedef __attribute__((address_space(1))) const uint32_t guint_t;
typedef __attribute__((address_space(3))) uint32_t luint_t;

// async global->LDS, 16B per lane; LDS dest = wave-uniform base + lane*16
__device__ __forceinline__ void gld16(const void* g, void* l) {
  __builtin_amdgcn_global_load_lds((guint_t*)g, (luint_t*)l, 16, 0, 0);
}

// raw barrier: no compiler-inserted vmcnt(0) drain (unlike __syncthreads)
__device__ __forceinline__ void barrier_raw() {
  asm volatile("" ::: "memory");
  __builtin_amdgcn_s_barrier();
  asm volatile("" ::: "memory");
}
#define WAITVM(n) asm volatile("s_waitcnt vmcnt(" #n ")" ::: "memory")

__device__ __forceinline__ unsigned short f2bf(float f) {
  union { float f; uint32_t u; } v; v.f = f;
  return (unsigned short)((v.u + 0x7FFFu + ((v.u >> 16) & 1u)) >> 16);
}

__device__ __forceinline__ uint32_t fbits(float f) {
  union { float f; uint32_t u; } v; v.f = f; return v.u;
}

// pack two fp32 (raw bits) -> (bf16,bf16) dword, round-half-up
__device__ __forceinline__ uint32_t pku(uint32_t u0, uint32_t u1) {
  return __builtin_amdgcn_perm(u1 + 0x8000u, u0 + 0x8000u, 0x07060302u);
}

// exchange hi 32 lanes of a with lo 32 lanes of b:
// a' = {a.lo, b.lo}, b' = {a.hi, b.hi}
__device__ __forceinline__ void swap32(uint32_t& a, uint32_t& b) {
#if __has_builtin(__builtin_amdgcn_permlane32_swap)
  uint2v r = __builtin_amdgcn_permlane32_swap(a, b, false, false);
  a = r[0]; b = r[1];
#else
  uint32_t aw = __shfl_xor(a, 32);
  uint32_t bw = __shfl_xor(b, 32);
  bool lo = (threadIdx.x & 32) == 0;
  uint32_t an = lo ? a : bw;
  uint32_t bn = lo ? aw : b;
  a = an; b = bn;
#endif
}

// ---------------------------------------------------------------------------
// prep: w_qkv -> bf16 (Q rows pre-scaled by SCALE*log2e), w_out -> bf16,
//       x [b][i][n] fp32 -> xT [b][n][i] bf16
// ---------------------------------------------------------------------------
__global__ __launch_bounds__(256) void prep_kernel(
    const float* __restrict__ x, const float* __restrict__ wqkv,
    const float* __restrict__ wout,
    unsigned short* __restrict__ wqkv_b, unsigned short* __restrict__ wout_b,
    unsigned short* __restrict__ xT) {
  __shared__ float tile[64][65];
  int blk = blockIdx.x;
  int t = threadIdx.x;
  if (blk < 384) {
    int idx = blk * 1024 + t * 4;
    float4 v = *(const float4*)(wqkv + idx);
    float s = ((idx >> 8) < HID) ? 0.18033688011112042f : 1.0f;  // 0.125*log2(e)
    ushort4 o;
    o.x = f2bf(v.x * s); o.y = f2bf(v.y * s);
    o.z = f2bf(v.z * s); o.w = f2bf(v.w * s);
    *(ushort4*)(wqkv_b + idx) = o;
    return;
  }
  if (blk < 512) {
    int idx = (blk - 384) * 1024 + t * 4;
    float4 v = *(const float4*)(wout + idx);
    ushort4 o;
    o.x = f2bf(v.x); o.y = f2bf(v.y); o.z = f2bf(v.z); o.w = f2bf(v.w);
    *(ushort4*)(wout_b + idx) = o;
    return;
  }
  int tid = blk - 512;
  int b  = tid >> 7;
  int r  = tid & 127;
  int i0 = (r >> 5) * 64;
  int n0 = (r & 31) * 64;
  const float* xb = x + (size_t)b * DIMC * SEQ;
  int tn = t & 15, ti = t >> 4;
#pragma unroll
  for (int j = 0; j < 4; j++) {
    int il = ti + j * 16;
    float4 v = *(const float4*)(xb + (size_t)(i0 + il) * SEQ + n0 + tn * 4);
    tile[il][tn*4+0] = v.x; tile[il][tn*4+1] = v.y;
    tile[il][tn*4+2] = v.z; tile[il][tn*4+3] = v.w;
  }
  __syncthreads();
  unsigned short* xTb = xT + (size_t)b * SEQ * DIMC;
#pragma unroll
  for (int j = 0; j < 4; j++) {
    int nl = ti + j * 16;
    int i4 = tn * 4;
    uint2 pk;
    pk.x = (uint32_t)f2bf(tile[i4+0][nl]) | ((uint32_t)f2bf(tile[i4+1][nl]) << 16);
    pk.y = (uint32_t)f2bf(tile[i4+2][nl]) | ((uint32_t)f2bf(tile[i4+3][nl]) << 16);
    *(uint2*)(xTb + (size_t)(n0 + nl) * DIMC + i0 + i4) = pk;
  }
}

// ---------------------------------------------------------------------------
// qkv_gemm: [1536,256]x[256,2048] per batch, 128x128 tile, BK=64.
// Double-buffered gld16 staging; ONE barrier per K-step, race-free order:
//   WAITVM(0) [own stage(kk) landed] -> barrier [all waves' stage(kk) landed]
//   -> stage(kk+1) [WAR-safe: compute(kk-1) readers fenced] -> compute(kk).
// ---------------------------------------------------------------------------
__global__ __launch_bounds__(256, 2) void qkv_gemm(
    const unsigned short* __restrict__ wq, const unsigned short* __restrict__ xT,
    unsigned short* __restrict__ Qs, unsigned short* __restrict__ Ks,
    unsigned short* __restrict__ Vt) {
  __shared__ unsigned short lds[32768];
  int o0 = blockIdx.x * 128;
  int n0 = blockIdx.y * 128;
  int b  = blockIdx.z;
  int t  = threadIdx.x;
  int wv = t >> 6, l = t & 63, l15 = l & 15, q = l >> 4;
  int wm = (wv & 1) * 64, wn = (wv >> 1) * 64;
  f32x4 acc[4][4];
#pragma unroll
  for (int i = 0; i < 4; i++)
#pragma unroll
    for (int j = 0; j < 4; j++) acc[i][j] = (f32x4){0.f, 0.f, 0.f, 0.f};
  const unsigned short* Ag = wq + (size_t)o0 * DIMC;
  const unsigned short* Bg = xT + ((size_t)b * SEQ + n0) * DIMC;
  int lrow8 = l >> 3, lcol = l & 7;

  auto stage = [&](int kk, int buf) {
    unsigned short* la = lds + (buf << 14);
    unsigned short* lb = la + 8192;
    int k0 = kk * 64;
#pragma unroll
    for (int c0 = 0; c0 < 4; c0++) {
      int c = wv * 4 + c0;
      int row = c * 8 + lrow8;
      int sg = lcol ^ (row & 7);
      gld16(Ag + (size_t)row * DIMC + k0 + sg * 8, la + c * 512);
      gld16(Bg + (size_t)row * DIMC + k0 + sg * 8, lb + c * 512);
    }
  };

  stage(0, 0);
  for (int kk = 0; kk < 4; kk++) {
    int cur = kk & 1;
    WAITVM(0);                             // own stage(kk) loads landed
    barrier_raw();                         // => all waves' stage(kk) landed
    if (kk < 3) stage(kk + 1, cur ^ 1);    // WAR-safe after barrier
    unsigned short* la = lds + (cur << 14);
    unsigned short* lb = la + 8192;
#pragma unroll
    for (int kh = 0; kh < 2; kh++) {
      bf16x8 af[4], bfr[4];
#pragma unroll
      for (int mt = 0; mt < 4; mt++) {
        int row = wm + mt*16 + l15;
        af[mt] = *(const bf16x8*)(la + row*64 + ((kh*4 + q) ^ (row & 7)) * 8);
      }
#pragma unroll
      for (int nt = 0; nt < 4; nt++) {
        int row = wn + nt*16 + l15;
        bfr[nt] = *(const bf16x8*)(lb + row*64 + ((kh*4 + q) ^ (row & 7)) * 8);
      }
#pragma unroll
      for (int mt = 0; mt < 4; mt++)
#pragma unroll
        for (int nt = 0; nt < 4; nt++)
          acc[mt][nt] = __builtin_amdgcn_mfma_f32_16x16x32_bf16(af[mt], bfr[nt], acc[mt][nt], 0, 0, 0);
    }
  }
  barrier_raw();                 // all waves done with LDS buffers before reuse
  int seg3 = o0 >> 9;            // 0=Q, 1=K, 2=V
  int h0   = (o0 & 511) >> 6;
  if (seg3 == 2) {
#pragma unroll
    for (int mt = 0; mt < 4; mt++)
#pragma unroll
      for (int nt = 0; nt < 4; nt++)
#pragma unroll
        for (int r = 0; r < 4; r++) {
          int ol = wm + mt * 16 + q * 4 + r;
          int h = h0 + (ol >> 6), d = ol & 63;
          int n = n0 + wn + nt * 16 + l15;
          Vt[(((size_t)b * NH + h) * DH + d) * SEQ + n] = f2bf(acc[mt][nt][r]);
        }
  } else {
    unsigned short* dst = (seg3 == 0) ? Qs : Ks;
#pragma unroll
    for (int mt = 0; mt < 4; mt++)
#pragma unroll
      for (int nt = 0; nt < 4; nt++)
#pragma unroll
        for (int r = 0; r < 4; r++) {
          int ol = wm + mt * 16 + q * 4 + r;
          int nn = wn + nt * 16 + l15;
          lds[nn * 136 + ol] = f2bf(acc[mt][nt][r]);
        }
    __syncthreads();
#pragma unroll
    for (int i = 0; i < 8; i++) {
      int idx = i * 256 + t;
      int nn  = idx >> 4;
      int olb = (idx & 15) * 8;
      uint4 v = *(const uint4*)(lds + nn * 136 + olb);
      int h = h0 + (olb >> 6), d = olb & 63;
      *(uint4*)(dst + (((size_t)b * NH + h) * SEQ + n0 + nn) * DH + d) = v;
    }
  }
}

// ---------------------------------------------------------------------------
// attn: 32x32x16 MFMA, q-tile 64, kv-split-2, 1024 XCD-swizzled blocks,
// 4 blocks/CU. vs round 2:
//  * V LDS tile is PAIRED-ROW: [32 rows x 128B], row r holds d=r and d=r+32,
//    8x16B slots swizzled s=(dt*4+kc2*2+lh)^(r&7) -> V ds_read_b128 spreads
//    all 8 slots/32 banks (was 64B rows -> 4 slots -> 8-way conflict, 8.4M cyc).
//  * ONE barrier/iter, race-free: WAITVM(0) -> barrier -> stage(it+1) -> compute.
// ---------------------------------------------------------------------------
__global__ __launch_bounds__(256, 4) void attn_kernel(
    const unsigned short* __restrict__ Qs, const unsigned short* __restrict__ Ks,
    const unsigned short* __restrict__ Vt, unsigned short* __restrict__ AO) {
  __shared__ unsigned short KVs[16384];  // 2 buf x (K[2][32][64] | Vpair[2][32][64]) = 32KB
  __shared__ float Lc[128];              // row-sum partials [cg][64 q]
  // XCD swizzle: id&7 = XCD slot; 4 bh x 32 q-tiles per XCD -> K/V L2-resident
  int id = blockIdx.x;
  int s  = id >> 3;
  int bh = (id & 7) * 4 + (s & 3);
  int q0 = (s >> 2) * 64;
  int b = bh >> 3, h = bh & 7;
  int t = threadIdx.x;
  int w = t >> 6, l = t & 63, l31 = l & 31, lh = l >> 5;
  int cg = w & 1, qg = w >> 1;
  // Q B-frags (n=query=l31, k=head-dim) straight from global, once
  const unsigned short* Qg = Qs + ((size_t)bh * SEQ + q0 + qg * 32) * DH;
  bf16x8 qb[4];
#pragma unroll
  for (int kc = 0; kc < 4; kc++)
    qb[kc] = *(const bf16x8*)(Qg + l31 * DH + kc*16 + lh*8);
  f32x16 oacc[2];
  float lsum = 0.f;
#pragma unroll
  for (int dt = 0; dt < 2; dt++)
#pragma unroll
    for (int r = 0; r < 16; r++) oacc[dt][r] = 0.f;

  const unsigned short* Ksrc = Ks + ((size_t)bh * SEQ + cg * 1024) * DH;
  const unsigned short* Vsrc = Vt + (size_t)bh * DH * SEQ + cg * 1024;

  auto stage = [&](int it2, int buf) {
    int jb = it2 * 32;
    unsigned short* base = KVs + buf * 8192;
    if (w < 2) {                           // stage K chunk cg: 32 keys x 128B
      const unsigned short* src = Ksrc + (size_t)jb * DH;
      unsigned short* dst = base + cg * 2048;
#pragma unroll
      for (int g = 0; g < 4; g++) {
        int kr = g * 8 + (l >> 3);
        gld16(src + (size_t)kr * DH + ((l & 7) ^ (kr & 7)) * 8, dst + g * 512);
      }
    } else {                               // stage V chunk cg: paired-row layout
      // LDS row r (128B) holds V^T[d=r][32k] and V^T[d=r+32][32k] interleaved:
      // slot s8 (16B) holds d=(u>>2)*32+r, keys j*8..j*8+7, u=s8^(r&7), j=u&3
      const unsigned short* src = Vsrc + jb;
      unsigned short* dst = base + 4096 + cg * 2048;
#pragma unroll
      for (int g = 0; g < 4; g++) {
        int r = g * 8 + (l >> 3);
        int u = (l & 7) ^ (r & 7);
        int d = (u >> 2) * 32 + r;
        int j = u & 3;
        gld16(src + (size_t)d * SEQ + j * 8, dst + g * 512);
      }
    }
  };

  stage(0, 0);
  for (int it = 0; it < 32; it++) {
    int cur = it & 1;
    WAITVM(0);                             // own stage(it) loads landed
    barrier_raw();                         // => all waves' stage(it) landed
    if (it < 31) stage(it + 1, cur ^ 1);   // WAR-safe after barrier
    const unsigned short* Kst = KVs + cur * 8192 + cg * 2048;
    const unsigned short* Vst = KVs + cur * 8192 + 4096 + cg * 2048;
    // S^T = K Q^T : A = K (m=key 32), B = Q (n=query 32)
    f32x16 st;
#pragma unroll
    for (int r = 0; r < 16; r++) st[r] = 0.f;
#pragma unroll
    for (int kc = 0; kc < 4; kc++) {
      bf16x8 kf = *(const bf16x8*)(Kst + l31 * 64 + ((kc*2 + lh) ^ (l31 & 7)) * 8);
      st = __builtin_amdgcn_mfma_f32_32x32x16_bf16(kf, qb[kc], st, 0, 0, 0);
    }
    // V B-frags (n=d, k=key 32) from paired-row tile
    bf16x8 vf[2][2];
#pragma unroll
    for (int kc2 = 0; kc2 < 2; kc2++)
#pragma unroll
      for (int dt = 0; dt < 2; dt++)
        vf[kc2][dt] = *(const bf16x8*)(Vst + l31 * 64 +
                                       ((dt*4 + kc2*2 + lh) ^ (l31 & 7)) * 8);
    // p = exp2(s); row-sum partial (col=query=l31 per lane)
    float p[16];
    float s0 = 0.f;
#pragma unroll
    for (int r = 0; r < 16; r++) { p[r] = __builtin_amdgcn_exp2f(st[r]); s0 += p[r]; }
    lsum += s0;
    // D-layout -> A-layout in registers (permlane32_swap + bf16 pack)
    bf16x8 af[2];
#pragma unroll
    for (int hf = 0; hf < 2; hf++) {
      uint32_t xs[4], ys[4];
#pragma unroll
      for (int j = 0; j < 4; j++) {
        xs[j] = fbits(p[hf*8 + j]);
        ys[j] = fbits(p[hf*8 + 4 + j]);
        swap32(xs[j], ys[j]);
      }
      uint32_t d0 = pku(xs[0], xs[1]);
      uint32_t d1 = pku(xs[2], xs[3]);
      uint32_t d2 = pku(ys[0], ys[1]);
      uint32_t d3 = pku(ys[2], ys[3]);
      union { uint32_t u[4]; bf16x8 v; } cv;
      cv.u[0] = d0; cv.u[1] = d1; cv.u[2] = d2; cv.u[3] = d3;
      af[hf] = cv.v;
    }
#pragma unroll
    for (int kc2 = 0; kc2 < 2; kc2++)
#pragma unroll
      for (int dt = 0; dt < 2; dt++)
        oacc[dt] = __builtin_amdgcn_mfma_f32_32x32x16_bf16(af[kc2], vf[kc2][dt], oacc[dt], 0, 0, 0);
  }
  // ---- combine the two kv-chunks (purely additive; no max-rescale) ----
  {
    float v = lsum;
    v += __shfl_xor(v, 32);                // lo/hi halves hold disjoint keys
    if (l < 32) Lc[cg * 64 + qg * 32 + l31] = v;
  }
  __syncthreads();
  float* Oc = (float*)KVs;                 // [64 q][64 d] fp32 = 16 KB
  if (cg == 1) {
#pragma unroll
    for (int dt = 0; dt < 2; dt++)
#pragma unroll
      for (int r = 0; r < 16; r++) {
        int qrow = qg*32 + (r & 3) + 8*(r >> 2) + 4*lh;
        Oc[qrow * 64 + dt*32 + l31] = oacc[dt][r];
      }
  }
  __syncthreads();
  if (cg == 0) {
    unsigned short* AOb = AO + (size_t)b * SEQ * HID + h * DH;
#pragma unroll
    for (int r = 0; r < 16; r++) {
      int qrow = qg*32 + (r & 3) + 8*(r >> 2) + 4*lh;
      float inv = __builtin_amdgcn_rcpf(Lc[qrow] + Lc[64 + qrow]);
      int n = q0 + qrow;
#pragma unroll
      for (int dt = 0; dt < 2; dt++) {
        float val = (oacc[dt][r] + Oc[qrow * 64 + dt*32 + l31]) * inv;
        AOb[(size_t)n * HID + dt*32 + l31] = f2bf(val);
      }
    }
  }
}

// ---------------------------------------------------------------------------
// out_gemm: [256,512] x AO^T -> out[b][256][2048] fp32 + bias
// Double-buffered gld16 staging, ONE barrier per K-step (race-free order).
// ---------------------------------------------------------------------------
__global__ __launch_bounds__(256, 2) void out_gemm(
    const unsigned short* __restrict__ wo, const unsigned short* __restrict__ AO,
    const float* __restrict__ bias, float* __restrict__ out) {
  __shared__ unsigned short lds[24576];
  int o0 = blockIdx.x * 64;
  int n0 = blockIdx.y * 128;
  int b  = blockIdx.z;
  int t  = threadIdx.x;
  int wv = t >> 6, l = t & 63, l15 = l & 15, q = l >> 4;
  int wm = (wv & 1) * 32, wn = (wv >> 1) * 64;
  f32x4 acc[2][4];
#pragma unroll
  for (int i = 0; i < 2; i++)
#pragma unroll
    for (int j = 0; j < 4; j++) acc[i][j] = (f32x4){0.f,0.f,0.f,0.f};
  const unsigned short* Ag = wo + (size_t)o0 * HID;
  const unsigned short* Bg = AO + ((size_t)b * SEQ + n0) * HID;
  int lrow8 = l >> 3, lcol = l & 7;

  auto stage = [&](int kk, int buf) {
    unsigned short* la = lds + buf * 12288;
    unsigned short* lb = la + 4096;
    int k0 = kk * 64;
#pragma unroll
    for (int c0 = 0; c0 < 2; c0++) {       // A: 8 chunks
      int c = wv * 2 + c0;
      int row = c * 8 + lrow8;
      int sg = lcol ^ (row & 7);
      gld16(Ag + (size_t)row * HID + k0 + sg * 8, la + c * 512);
    }
#pragma unroll
    for (int c0 = 0; c0 < 4; c0++) {       // B: 16 chunks
      int c = wv * 4 + c0;
      int row = c * 8 + lrow8;
      int sg = lcol ^ (row & 7);
      gld16(Bg + (size_t)row * HID + k0 + sg * 8, lb + c * 512);
    }
  };

  stage(0, 0);
  for (int kk = 0; kk < 8; kk++) {
    int cur = kk & 1;
    WAITVM(0);                             // own stage(kk) loads landed
    barrier_raw();                         // => all waves' stage(kk) landed
    if (kk < 7) stage(kk + 1, cur ^ 1);    // WAR-safe after barrier
    unsigned short* la = lds + cur * 12288;
    unsigned short* lb = la + 4096;
#pragma unroll
    for (int kh = 0; kh < 2; kh++) {
      bf16x8 af[2], bfr[4];
#pragma unroll
      for (int mt = 0; mt < 2; mt++) {
        int row = wm + mt*16 + l15;
        af[mt] = *(const bf16x8*)(la + row*64 + ((kh*4 + q) ^ (row & 7)) * 8);
      }
#pragma unroll
      for (int nt = 0; nt < 4; nt++) {
        int row = wn + nt*16 + l15;
        bfr[nt] = *(const bf16x8*)(lb + row*64 + ((kh*4 + q) ^ (row & 7)) * 8);
      }
#pragma unroll
      for (int mt = 0; mt < 2; mt++)
#pragma unroll
        for (int nt = 0; nt < 4; nt++)
          acc[mt][nt] = __builtin_amdgcn_mfma_f32_16x16x32_bf16(af[mt], bfr[nt], acc[mt][nt], 0,0,0);
    }
  }
#pragma unroll
  for (int mt = 0; mt < 2; mt++)
#pragma unroll
    for (int nt = 0; nt < 4; nt++)
#pragma unroll
      for (int r = 0; r < 4; r++) {
        int o2 = o0 + wm + mt*16 + q*4 + r;
        int n  = n0 + wn + nt*16 + l15;
        out[((size_t)b * DIMC + o2) * SEQ + n] = acc[mt][nt][r] + bias[o2];
      }
}

extern "C" void kernel_launch(void* const* d_in, const int* in_sizes, int n_in,
                              void* d_out, int out_size, void* d_ws, size_t ws_size,
                              hipStream_t stream) {
  const float* x    = (const float*)d_in[0];
  const float* wqkv = (const float*)d_in[1];
  const float* wout = (const float*)d_in[2];
  const float* bout = (const float*)d_in[3];
  float* out = (float*)d_out;
  char* ws = (char*)d_ws;
  unsigned short* wqkv_b = (unsigned short*)(ws);
  unsigned short* wout_b = (unsigned short*)(ws + 786432);
  unsigned short* xT     = (unsigned short*)(ws + 1048576);
  unsigned short* Qs     = (unsigned short*)(ws + 5242880);
  unsigned short* Ks     = (unsigned short*)(ws + 13631488);
  unsigned short* Vt     = (unsigned short*)(ws + 22020096);
  unsigned short* AO     = (unsigned short*)(ws + 30408704);
  prep_kernel<<<1024, 256, 0, stream>>>(x, wqkv, wout, wqkv_b, wout_b, xT);
  qkv_gemm<<<dim3(12, 16, 4), 256, 0, stream>>>(wqkv_b, xT, Qs, Ks, Vt);
  attn_kernel<<<1024, 256, 0, stream>>>(Qs, Ks, Vt, AO);
  out_gemm<<<dim3(4, 16, 4), 256, 0, stream>>>(wout_b, AO, bout, out);
}

// Round 5
// 133.027 us; speedup vs baseline: 1.0487x; 1.0455x over previous
//
#include <hip/hip_runtime.h>
#include <stdint.h>

#define SEQ  2048
#define DIMC 256
#define HID  512
#define NH   8
#define DH   64

typedef __attribute__((ext_vector_type(8))) short bf16x8;
typedef __attribute__((ext_vector_type(4))) float f32x4;
typedef __attribute__((ext_vector_type(16))) float f32x16;
typedef __attribute__((ext_vector_type(2))) unsigned uint2v;
typedef __attribute__((address_space(1))) const uint32_t guint_t;
typedef __attribute__((address_space(3))) uint32_t luint_t;

// async global->LDS, 16B per lane; LDS dest = wave-uniform base + lane*16
__device__ __forceinline__ void gld16(const void* g, void* l) {
  __builtin_amdgcn_global_load_lds((guint_t*)g, (luint_t*)l, 16, 0, 0);
}

// raw barrier: no compiler-inserted vmcnt(0) drain (unlike __syncthreads)
__device__ __forceinline__ void barrier_raw() {
  asm volatile("" ::: "memory");
  __builtin_amdgcn_s_barrier();
  asm volatile("" ::: "memory");
}
#define WAITVM(n) asm volatile("s_waitcnt vmcnt(" #n ")" ::: "memory")

__device__ __forceinline__ unsigned short f2bf(float f) {
  union { float f; uint32_t u; } v; v.f = f;
  return (unsigned short)((v.u + 0x7FFFu + ((v.u >> 16) & 1u)) >> 16);
}

__device__ __forceinline__ uint32_t fbits(float f) {
  union { float f; uint32_t u; } v; v.f = f; return v.u;
}
__device__ __forceinline__ float ffrombits(uint32_t u) {
  union { uint32_t u; float f; } v; v.u = u; return v.f;
}

// pack two fp32 -> (bf16,bf16) dword in ONE instr (RNE), replaces 3-op pku
__device__ __forceinline__ uint32_t cvtpk(float a, float b) {
  uint32_t r;
  asm("v_cvt_pk_bf16_f32 %0, %1, %2" : "=v"(r) : "v"(a), "v"(b));
  return r;
}

// exchange hi 32 lanes of a with lo 32 lanes of b:
// a' = {a.lo, b.lo}, b' = {a.hi, b.hi}
__device__ __forceinline__ void swap32(uint32_t& a, uint32_t& b) {
#if __has_builtin(__builtin_amdgcn_permlane32_swap)
  uint2v r = __builtin_amdgcn_permlane32_swap(a, b, false, false);
  a = r[0]; b = r[1];
#else
  uint32_t aw = __shfl_xor(a, 32);
  uint32_t bw = __shfl_xor(b, 32);
  bool lo = (threadIdx.x & 32) == 0;
  uint32_t an = lo ? a : bw;
  uint32_t bn = lo ? aw : b;
  a = an; b = bn;
#endif
}

// ---------------------------------------------------------------------------
// prep: w_qkv -> bf16 (Q rows pre-scaled by SCALE*log2e), w_out -> bf16,
//       x [b][i][n] fp32 -> xT [b][n][i] bf16
// ---------------------------------------------------------------------------
__global__ __launch_bounds__(256) void prep_kernel(
    const float* __restrict__ x, const float* __restrict__ wqkv,
    const float* __restrict__ wout,
    unsigned short* __restrict__ wqkv_b, unsigned short* __restrict__ wout_b,
    unsigned short* __restrict__ xT) {
  __shared__ float tile[64][65];
  int blk = blockIdx.x;
  int t = threadIdx.x;
  if (blk < 384) {
    int idx = blk * 1024 + t * 4;
    float4 v = *(const float4*)(wqkv + idx);
    float s = ((idx >> 8) < HID) ? 0.18033688011112042f : 1.0f;  // 0.125*log2(e)
    ushort4 o;
    o.x = f2bf(v.x * s); o.y = f2bf(v.y * s);
    o.z = f2bf(v.z * s); o.w = f2bf(v.w * s);
    *(ushort4*)(wqkv_b + idx) = o;
    return;
  }
  if (blk < 512) {
    int idx = (blk - 384) * 1024 + t * 4;
    float4 v = *(const float4*)(wout + idx);
    ushort4 o;
    o.x = f2bf(v.x); o.y = f2bf(v.y); o.z = f2bf(v.z); o.w = f2bf(v.w);
    *(ushort4*)(wout_b + idx) = o;
    return;
  }
  int tid = blk - 512;
  int b  = tid >> 7;
  int r  = tid & 127;
  int i0 = (r >> 5) * 64;
  int n0 = (r & 31) * 64;
  const float* xb = x + (size_t)b * DIMC * SEQ;
  int tn = t & 15, ti = t >> 4;
#pragma unroll
  for (int j = 0; j < 4; j++) {
    int il = ti + j * 16;
    float4 v = *(const float4*)(xb + (size_t)(i0 + il) * SEQ + n0 + tn * 4);
    tile[il][tn*4+0] = v.x; tile[il][tn*4+1] = v.y;
    tile[il][tn*4+2] = v.z; tile[il][tn*4+3] = v.w;
  }
  __syncthreads();
  unsigned short* xTb = xT + (size_t)b * SEQ * DIMC;
#pragma unroll
  for (int j = 0; j < 4; j++) {
    int nl = ti + j * 16;
    int i4 = tn * 4;
    uint2 pk;
    pk.x = (uint32_t)f2bf(tile[i4+0][nl]) | ((uint32_t)f2bf(tile[i4+1][nl]) << 16);
    pk.y = (uint32_t)f2bf(tile[i4+2][nl]) | ((uint32_t)f2bf(tile[i4+3][nl]) << 16);
    *(uint2*)(xTb + (size_t)(n0 + nl) * DIMC + i0 + i4) = pk;
  }
}

// ---------------------------------------------------------------------------
// qkv_gemm: [1536,256]x[256,2048] per batch, 128x128 tile, BK=64.
// launch_bounds(256,3): grid 768 = 3 blocks/CU -> ONE dispatch round.
// V epilogue now routed through LDS [ol][nn] transpose -> 16B stores
// (was 64 scalar 2B stores/thread -> V blocks were the dispatch tail).
// ---------------------------------------------------------------------------
__global__ __launch_bounds__(256, 3) void qkv_gemm(
    const unsigned short* __restrict__ wq, const unsigned short* __restrict__ xT,
    unsigned short* __restrict__ Qs, unsigned short* __restrict__ Ks,
    unsigned short* __restrict__ Vt) {
  __shared__ unsigned short lds[32768];
  int o0 = blockIdx.x * 128;
  int n0 = blockIdx.y * 128;
  int b  = blockIdx.z;
  int t  = threadIdx.x;
  int wv = t >> 6, l = t & 63, l15 = l & 15, q = l >> 4;
  int wm = (wv & 1) * 64, wn = (wv >> 1) * 64;
  f32x4 acc[4][4];
#pragma unroll
  for (int i = 0; i < 4; i++)
#pragma unroll
    for (int j = 0; j < 4; j++) acc[i][j] = (f32x4){0.f, 0.f, 0.f, 0.f};
  const unsigned short* Ag = wq + (size_t)o0 * DIMC;
  const unsigned short* Bg = xT + ((size_t)b * SEQ + n0) * DIMC;
  int lrow8 = l >> 3, lcol = l & 7;

  auto stage = [&](int kk, int buf) {
    unsigned short* la = lds + (buf << 14);
    unsigned short* lb = la + 8192;
    int k0 = kk * 64;
#pragma unroll
    for (int c0 = 0; c0 < 4; c0++) {
      int c = wv * 4 + c0;
      int row = c * 8 + lrow8;
      int sg = lcol ^ (row & 7);
      gld16(Ag + (size_t)row * DIMC + k0 + sg * 8, la + c * 512);
      gld16(Bg + (size_t)row * DIMC + k0 + sg * 8, lb + c * 512);
    }
  };

  stage(0, 0);
  for (int kk = 0; kk < 4; kk++) {
    int cur = kk & 1;
    WAITVM(0);                             // own stage(kk) loads landed
    barrier_raw();                         // => all waves' stage(kk) landed
    if (kk < 3) stage(kk + 1, cur ^ 1);    // WAR-safe after barrier
    unsigned short* la = lds + (cur << 14);
    unsigned short* lb = la + 8192;
#pragma unroll
    for (int kh = 0; kh < 2; kh++) {
      bf16x8 af[4], bfr[4];
#pragma unroll
      for (int mt = 0; mt < 4; mt++) {
        int row = wm + mt*16 + l15;
        af[mt] = *(const bf16x8*)(la + row*64 + ((kh*4 + q) ^ (row & 7)) * 8);
      }
#pragma unroll
      for (int nt = 0; nt < 4; nt++) {
        int row = wn + nt*16 + l15;
        bfr[nt] = *(const bf16x8*)(lb + row*64 + ((kh*4 + q) ^ (row & 7)) * 8);
      }
#pragma unroll
      for (int mt = 0; mt < 4; mt++)
#pragma unroll
        for (int nt = 0; nt < 4; nt++)
          acc[mt][nt] = __builtin_amdgcn_mfma_f32_16x16x32_bf16(af[mt], bfr[nt], acc[mt][nt], 0, 0, 0);
    }
  }
  barrier_raw();                 // all waves done with LDS buffers before reuse
  int seg3 = o0 >> 9;            // 0=Q, 1=K, 2=V
  int h0   = (o0 & 511) >> 6;
  if (seg3 == 2) {
    // V: transpose via LDS [ol][nn] -> 16B n-contiguous stores
#pragma unroll
    for (int mt = 0; mt < 4; mt++)
#pragma unroll
      for (int nt = 0; nt < 4; nt++)
#pragma unroll
        for (int r = 0; r < 4; r++) {
          int ol = wm + mt * 16 + q * 4 + r;
          int nn = wn + nt * 16 + l15;
          lds[ol * 136 + nn] = f2bf(acc[mt][nt][r]);
        }
    __syncthreads();
#pragma unroll
    for (int i = 0; i < 8; i++) {
      int idx = i * 256 + t;
      int ol  = idx >> 4;
      int nnb = (idx & 15) * 8;
      uint4 v = *(const uint4*)(lds + ol * 136 + nnb);
      int h = h0 + (ol >> 6), d = ol & 63;
      *(uint4*)(Vt + (((size_t)b * NH + h) * DH + d) * SEQ + n0 + nnb) = v;
    }
  } else {
    unsigned short* dst = (seg3 == 0) ? Qs : Ks;
#pragma unroll
    for (int mt = 0; mt < 4; mt++)
#pragma unroll
      for (int nt = 0; nt < 4; nt++)
#pragma unroll
        for (int r = 0; r < 4; r++) {
          int ol = wm + mt * 16 + q * 4 + r;
          int nn = wn + nt * 16 + l15;
          lds[nn * 136 + ol] = f2bf(acc[mt][nt][r]);
        }
    __syncthreads();
#pragma unroll
    for (int i = 0; i < 8; i++) {
      int idx = i * 256 + t;
      int nn  = idx >> 4;
      int olb = (idx & 15) * 8;
      uint4 v = *(const uint4*)(lds + nn * 136 + olb);
      int h = h0 + (olb >> 6), d = olb & 63;
      *(uint4*)(dst + (((size_t)b * NH + h) * SEQ + n0 + nn) * DH + d) = v;
    }
  }
}

// ---------------------------------------------------------------------------
// attn: 32x32x16 MFMA, q-tile 64, kv-split-2, 1024 XCD-swizzled blocks,
// 4 blocks/CU. vs r4: setprio(1) around MFMA clusters (T5, +4-7% attn),
// v_cvt_pk_bf16_f32 pack (1 op vs 3), pairwise tree row-sum (depth 4 vs 16),
// stage global addresses hoisted out of the loop.
// ---------------------------------------------------------------------------
__global__ __launch_bounds__(256, 4) void attn_kernel(
    const unsigned short* __restrict__ Qs, const unsigned short* __restrict__ Ks,
    const unsigned short* __restrict__ Vt, unsigned short* __restrict__ AO) {
  __shared__ unsigned short KVs[16384];  // 2 buf x (K[2][32][64] | Vpair[2][32][64]) = 32KB
  __shared__ float Lc[128];              // row-sum partials [cg][64 q]
  // XCD swizzle: id&7 = XCD slot; 4 bh x 32 q-tiles per XCD -> K/V L2-resident
  int id = blockIdx.x;
  int s  = id >> 3;
  int bh = (id & 7) * 4 + (s & 3);
  int q0 = (s >> 2) * 64;
  int b = bh >> 3, h = bh & 7;
  int t = threadIdx.x;
  int w = t >> 6, l = t & 63, l31 = l & 31, lh = l >> 5;
  int cg = w & 1, qg = w >> 1;
  // Q B-frags (n=query=l31, k=head-dim) straight from global, once
  const unsigned short* Qg = Qs + ((size_t)bh * SEQ + q0 + qg * 32) * DH;
  bf16x8 qb[4];
#pragma unroll
  for (int kc = 0; kc < 4; kc++)
    qb[kc] = *(const bf16x8*)(Qg + l31 * DH + kc*16 + lh*8);
  f32x16 oacc[2];
  float lsum = 0.f;
#pragma unroll
  for (int dt = 0; dt < 2; dt++)
#pragma unroll
    for (int r = 0; r < 16; r++) oacc[dt][r] = 0.f;

  const unsigned short* Ksrc = Ks + ((size_t)bh * SEQ + cg * 1024) * DH;
  const unsigned short* Vsrc = Vt + (size_t)bh * DH * SEQ + cg * 1024;

  // hoisted per-lane stage addresses (advance by constant step per iter)
  const unsigned short* sgp[4];
  unsigned short* dst0;
  size_t step;
  if (w < 2) {                             // this wave stages K chunk cg
#pragma unroll
    for (int g = 0; g < 4; g++) {
      int kr = g * 8 + (l >> 3);
      sgp[g] = Ksrc + (size_t)kr * DH + ((l & 7) ^ (kr & 7)) * 8;
    }
    dst0 = (unsigned short*)KVs + cg * 2048;
    step = (size_t)32 * DH;
  } else {                                 // this wave stages V chunk cg (paired-row)
#pragma unroll
    for (int g = 0; g < 4; g++) {
      int r = g * 8 + (l >> 3);
      int u = (l & 7) ^ (r & 7);
      int d = (u >> 2) * 32 + r;
      int j = u & 3;
      sgp[g] = Vsrc + (size_t)d * SEQ + j * 8;
    }
    dst0 = (unsigned short*)KVs + 4096 + cg * 2048;
    step = 32;
  }

  auto stage = [&](int it2, int buf) {
    size_t off = (size_t)it2 * step;
    unsigned short* dstb = dst0 + buf * 8192;
#pragma unroll
    for (int g = 0; g < 4; g++)
      gld16(sgp[g] + off, dstb + g * 512);
  };

  stage(0, 0);
  for (int it = 0; it < 32; it++) {
    int cur = it & 1;
    WAITVM(0);                             // own stage(it) loads landed
    barrier_raw();                         // => all waves' stage(it) landed
    if (it < 31) stage(it + 1, cur ^ 1);   // WAR-safe after barrier
    const unsigned short* Kst = KVs + cur * 8192 + cg * 2048;
    const unsigned short* Vst = KVs + cur * 8192 + 4096 + cg * 2048;
    // S^T = K Q^T : A = K (m=key 32), B = Q (n=query 32)
    f32x16 st;
#pragma unroll
    for (int r = 0; r < 16; r++) st[r] = 0.f;
    __builtin_amdgcn_s_setprio(1);
#pragma unroll
    for (int kc = 0; kc < 4; kc++) {
      bf16x8 kf = *(const bf16x8*)(Kst + l31 * 64 + ((kc*2 + lh) ^ (l31 & 7)) * 8);
      st = __builtin_amdgcn_mfma_f32_32x32x16_bf16(kf, qb[kc], st, 0, 0, 0);
    }
    __builtin_amdgcn_s_setprio(0);
    // V B-frags (n=d, k=key 32) from paired-row tile
    bf16x8 vf[2][2];
#pragma unroll
    for (int kc2 = 0; kc2 < 2; kc2++)
#pragma unroll
      for (int dt = 0; dt < 2; dt++)
        vf[kc2][dt] = *(const bf16x8*)(Vst + l31 * 64 +
                                       ((dt*4 + kc2*2 + lh) ^ (l31 & 7)) * 8);
    // p = exp2(s); pairwise tree row-sum (depth 4, not a 16-deep chain)
    float p[16];
#pragma unroll
    for (int r = 0; r < 16; r++) p[r] = __builtin_amdgcn_exp2f(st[r]);
    {
      float t0 = p[0]+p[1],  t1 = p[2]+p[3],  t2 = p[4]+p[5],  t3 = p[6]+p[7];
      float t4 = p[8]+p[9],  t5 = p[10]+p[11], t6 = p[12]+p[13], t7 = p[14]+p[15];
      float u0 = t0+t1, u1 = t2+t3, u2 = t4+t5, u3 = t6+t7;
      lsum += (u0+u1) + (u2+u3);
    }
    // D-layout -> A-layout in registers (permlane32_swap + cvt_pk_bf16)
    bf16x8 af[2];
#pragma unroll
    for (int hf = 0; hf < 2; hf++) {
      uint32_t xs[4], ys[4];
#pragma unroll
      for (int j = 0; j < 4; j++) {
        xs[j] = fbits(p[hf*8 + j]);
        ys[j] = fbits(p[hf*8 + 4 + j]);
        swap32(xs[j], ys[j]);
      }
      union { uint32_t u[4]; bf16x8 v; } cv;
      cv.u[0] = cvtpk(ffrombits(xs[0]), ffrombits(xs[1]));
      cv.u[1] = cvtpk(ffrombits(xs[2]), ffrombits(xs[3]));
      cv.u[2] = cvtpk(ffrombits(ys[0]), ffrombits(ys[1]));
      cv.u[3] = cvtpk(ffrombits(ys[2]), ffrombits(ys[3]));
      af[hf] = cv.v;
    }
    __builtin_amdgcn_s_setprio(1);
#pragma unroll
    for (int kc2 = 0; kc2 < 2; kc2++)
#pragma unroll
      for (int dt = 0; dt < 2; dt++)
        oacc[dt] = __builtin_amdgcn_mfma_f32_32x32x16_bf16(af[kc2], vf[kc2][dt], oacc[dt], 0, 0, 0);
    __builtin_amdgcn_s_setprio(0);
  }
  // ---- combine the two kv-chunks (purely additive; no max-rescale) ----
  {
    float v = lsum;
    v += __shfl_xor(v, 32);                // lo/hi halves hold disjoint keys
    if (l < 32) Lc[cg * 64 + qg * 32 + l31] = v;
  }
  __syncthreads();
  float* Oc = (float*)KVs;                 // [64 q][64 d] fp32 = 16 KB
  if (cg == 1) {
#pragma unroll
    for (int dt = 0; dt < 2; dt++)
#pragma unroll
      for (int r = 0; r < 16; r++) {
        int qrow = qg*32 + (r & 3) + 8*(r >> 2) + 4*lh;
        Oc[qrow * 64 + dt*32 + l31] = oacc[dt][r];
      }
  }
  __syncthreads();
  if (cg == 0) {
    unsigned short* AOb = AO + (size_t)b * SEQ * HID + h * DH;
#pragma unroll
    for (int r = 0; r < 16; r++) {
      int qrow = qg*32 + (r & 3) + 8*(r >> 2) + 4*lh;
      float inv = __builtin_amdgcn_rcpf(Lc[qrow] + Lc[64 + qrow]);
      int n = q0 + qrow;
#pragma unroll
      for (int dt = 0; dt < 2; dt++) {
        float val = (oacc[dt][r] + Oc[qrow * 64 + dt*32 + l31]) * inv;
        AOb[(size_t)n * HID + dt*32 + l31] = f2bf(val);
      }
    }
  }
}

// ---------------------------------------------------------------------------
// out_gemm: [256,512] x AO^T -> out[b][256][2048] fp32 + bias
// Re-tiled 64x64 (was 64x128): grid 512 blocks = 2/CU (was 1/CU, 1 wave/SIMD
// -> maximal latency exposure). Double-buffered gld16, one barrier/K-step.
// ---------------------------------------------------------------------------
__global__ __launch_bounds__(256, 2) void out_gemm(
    const unsigned short* __restrict__ wo, const unsigned short* __restrict__ AO,
    const float* __restrict__ bias, float* __restrict__ out) {
  __shared__ unsigned short lds[16384];    // 2 buf x (A 4096 + B 4096 shorts)
  int o0 = blockIdx.x * 64;
  int n0 = blockIdx.y * 64;
  int b  = blockIdx.z;
  int t  = threadIdx.x;
  int wv = t >> 6, l = t & 63, l15 = l & 15, q = l >> 4;
  int wm = (wv & 1) * 32, wn = (wv >> 1) * 32;
  f32x4 acc[2][2];
#pragma unroll
  for (int i = 0; i < 2; i++)
#pragma unroll
    for (int j = 0; j < 2; j++) acc[i][j] = (f32x4){0.f,0.f,0.f,0.f};
  const unsigned short* Ag = wo + (size_t)o0 * HID;
  const unsigned short* Bg = AO + ((size_t)b * SEQ + n0) * HID;
  int lrow8 = l >> 3, lcol = l & 7;

  auto stage = [&](int kk, int buf) {
    unsigned short* la = lds + buf * 8192;
    unsigned short* lb = la + 4096;
    int k0 = kk * 64;
#pragma unroll
    for (int c0 = 0; c0 < 2; c0++) {       // A: 8 chunks, 2/wave
      int c = wv * 2 + c0;
      int row = c * 8 + lrow8;
      int sg = lcol ^ (row & 7);
      gld16(Ag + (size_t)row * HID + k0 + sg * 8, la + c * 512);
      gld16(Bg + (size_t)row * HID + k0 + sg * 8, lb + c * 512);
    }
  };

  stage(0, 0);
  for (int kk = 0; kk < 8; kk++) {
    int cur = kk & 1;
    WAITVM(0);                             // own stage(kk) loads landed
    barrier_raw();                         // => all waves' stage(kk) landed
    if (kk < 7) stage(kk + 1, cur ^ 1);    // WAR-safe after barrier
    unsigned short* la = lds + cur * 8192;
    unsigned short* lb = la + 4096;
#pragma unroll
    for (int kh = 0; kh < 2; kh++) {
      bf16x8 af[2], bfr[2];
#pragma unroll
      for (int mt = 0; mt < 2; mt++) {
        int row = wm + mt*16 + l15;
        af[mt] = *(const bf16x8*)(la + row*64 + ((kh*4 + q) ^ (row & 7)) * 8);
      }
#pragma unroll
      for (int nt = 0; nt < 2; nt++) {
        int row = wn + nt*16 + l15;
        bfr[nt] = *(const bf16x8*)(lb + row*64 + ((kh*4 + q) ^ (row & 7)) * 8);
      }
#pragma unroll
      for (int mt = 0; mt < 2; mt++)
#pragma unroll
        for (int nt = 0; nt < 2; nt++)
          acc[mt][nt] = __builtin_amdgcn_mfma_f32_16x16x32_bf16(af[mt], bfr[nt], acc[mt][nt], 0,0,0);
    }
  }
#pragma unroll
  for (int mt = 0; mt < 2; mt++)
#pragma unroll
    for (int nt = 0; nt < 2; nt++)
#pragma unroll
      for (int r = 0; r < 4; r++) {
        int o2 = o0 + wm + mt*16 + q*4 + r;
        int n  = n0 + wn + nt*16 + l15;
        out[((size_t)b * DIMC + o2) * SEQ + n] = acc[mt][nt][r] + bias[o2];
      }
}

extern "C" void kernel_launch(void* const* d_in, const int* in_sizes, int n_in,
                              void* d_out, int out_size, void* d_ws, size_t ws_size,
                              hipStream_t stream) {
  const float* x    = (const float*)d_in[0];
  const float* wqkv = (const float*)d_in[1];
  const float* wout = (const float*)d_in[2];
  const float* bout = (const float*)d_in[3];
  float* out = (float*)d_out;
  char* ws = (char*)d_ws;
  unsigned short* wqkv_b = (unsigned short*)(ws);
  unsigned short* wout_b = (unsigned short*)(ws + 786432);
  unsigned short* xT     = (unsigned short*)(ws + 1048576);
  unsigned short* Qs     = (unsigned short*)(ws + 5242880);
  unsigned short* Ks     = (unsigned short*)(ws + 13631488);
  unsigned short* Vt     = (unsigned short*)(ws + 22020096);
  unsigned short* AO     = (unsigned short*)(ws + 30408704);
  prep_kernel<<<1024, 256, 0, stream>>>(x, wqkv, wout, wqkv_b, wout_b, xT);
  qkv_gemm<<<dim3(12, 16, 4), 256, 0, stream>>>(wqkv_b, xT, Qs, Ks, Vt);
  attn_kernel<<<1024, 256, 0, stream>>>(Qs, Ks, Vt, AO);
  out_gemm<<<dim3(4, 32, 4), 256, 0, stream>>>(wout_b, AO, bout, out);
}